// Round 2
// baseline (15.743 us; speedup 1.0000x reference)
//
#include <hip/hip_runtime.h>

// GANLoss gather-reduce:
//   out = -(1/N) * sum_n [ reward[n] * (1/6) * sum_f prob_flat[n, OFF[f]+target[n,f]] ]
// N = 64*1024 = 65536, C = 3200, F = 6.
// NOTE: harness passes integer inputs as int32 (NOT the reference's int64).
// Double-precision, fixed-order two-stage reduction for determinism + accuracy.

#define NROWS 65536
#define NCOLS 3200
#define NFLD  6
#define BLK   256
#define NBLOCKS (NROWS / BLK)   // 256

__global__ __launch_bounds__(BLK)
void gan_loss_partial(const float* __restrict__ prob,
                      const int* __restrict__ target,
                      const float* __restrict__ reward,
                      double* __restrict__ partial) {
    const int offs[NFLD] = {0, 256, 512, 1536, 2560, 3072};
    const int n = blockIdx.x * BLK + threadIdx.x;   // exactly one row per thread

    const float* __restrict__ row = prob + (size_t)n * NCOLS;
    const int* __restrict__ t = target + (size_t)n * NFLD;

    // 24 B of contiguous target indices per thread.
    double s = 0.0;
#pragma unroll
    for (int f = 0; f < NFLD; ++f) {
        const int col = offs[f] + t[f];
        s += (double)row[col];
    }
    double v = s * (double)reward[n];

    __shared__ double sm[BLK];
    sm[threadIdx.x] = v;
    __syncthreads();
#pragma unroll
    for (int stride = BLK / 2; stride > 0; stride >>= 1) {
        if (threadIdx.x < stride) sm[threadIdx.x] += sm[threadIdx.x + stride];
        __syncthreads();
    }
    if (threadIdx.x == 0) partial[blockIdx.x] = sm[0];
}

__global__ __launch_bounds__(NBLOCKS)
void gan_loss_final(const double* __restrict__ partial,
                    float* __restrict__ out) {
    __shared__ double sm[NBLOCKS];
    sm[threadIdx.x] = partial[threadIdx.x];
    __syncthreads();
#pragma unroll
    for (int stride = NBLOCKS / 2; stride > 0; stride >>= 1) {
        if (threadIdx.x < stride) sm[threadIdx.x] += sm[threadIdx.x + stride];
        __syncthreads();
    }
    if (threadIdx.x == 0) {
        // mean over fields (/6) and over rows (/N), negated
        out[0] = (float)(-sm[0] / ((double)NROWS * (double)NFLD));
    }
}

extern "C" void kernel_launch(void* const* d_in, const int* in_sizes, int n_in,
                              void* d_out, int out_size, void* d_ws, size_t ws_size,
                              hipStream_t stream) {
    const float* prob   = (const float*)d_in[0];   // (64,1024,3200) f32
    const int*   target = (const int*)d_in[1];     // (65536,6) int32 (harness convention)
    const float* reward = (const float*)d_in[2];   // (65536,) f32
    // d_in[3] = weights: unused by reference forward

    double* partial = (double*)d_ws;               // 256 doubles = 2 KB
    float*  out     = (float*)d_out;

    gan_loss_partial<<<NBLOCKS, BLK, 0, stream>>>(prob, target, reward, partial);
    gan_loss_final<<<1, NBLOCKS, 0, stream>>>(partial, out);
}